// Round 19
// baseline (5947.812 us; speedup 1.0000x reference)
//
#include <hip/hip_runtime.h>
#include <math.h>

// RNN scan, SEQ=2048, BATCH=64, I=H=O=256, fp32.
// GOLDEN (confirmed round 10, absmax 0.0): XLA-CPU fp32 —
//   dots : per-element single-acc ascending-k FMA chain (Eigen gebp)
//   +bh, +xp : one fadd each
//   tanh : Eigen fast-tanh, clamp +-7.99881172180175781, FMA Horner,
//          exact fdiv, |x|<4e-4 -> x (unclamped).
// DO NOT change op order in K1/K2 — the recurrence is chaotic (gain ~2.5/step).
//
// R19: R18 falsified AGPR-direct VALU (assembler: invalid operand). The chain
// latency (~12 cyc/link) is irreducible — so fill its stall slots with a
// SECOND independent chain: 2 batch rows per block (rows share column weights
// => one accvgpr_read feeds both rows' FMAs). Per-row op order unchanged.
// 32 blocks; LDS 4 h-buffers; AGPR budget unchanged.

#define SEQ 2048
#define BATCH 64
#define HID 256
#define BH 16384  // BATCH*HID

// Eigen/XLA fast-tanh f32, FMA evaluation, clamp 7.99881172180175781.
__device__ __forceinline__ float tanh_xla(float x) {
  const float kClamp = 7.99881172180175781f;
  float xc = fminf(fmaxf(x, -kClamp), kClamp);
  float x2 = __fmul_rn(xc, xc);
  float p = __fmaf_rn(x2, -2.76076847742355e-16f, 2.00018790482477e-13f);
  p = __fmaf_rn(x2, p, -8.60467152213735e-11f);
  p = __fmaf_rn(x2, p, 5.12229709037114e-08f);
  p = __fmaf_rn(x2, p, 1.48572235717979e-05f);
  p = __fmaf_rn(x2, p, 6.37261928875436e-04f);
  p = __fmaf_rn(x2, p, 4.89352455891786e-03f);
  p = __fmul_rn(xc, p);
  float q = __fmaf_rn(x2, 1.19825839466702e-06f, 1.18534705686654e-04f);
  q = __fmaf_rn(x2, q, 2.26843463243900e-03f);
  q = __fmaf_rn(x2, q, 4.89352518554385e-03f);
  float r = __fdiv_rn(p, q);
  return (fabsf(x) < 0.0004f) ? x : r;
}

// ---------------------------------------------------------------------------
// K1: xp = X @ Ux + bh. Per element: single-acc ascending-i FMA chain
// (Eigen order), then one fadd for bias. BIT-EXACT — do not reorder.
// ---------------------------------------------------------------------------
__global__ __launch_bounds__(256) void xp_dot_kernel(
    const float* __restrict__ X, const float* __restrict__ Ux,
    const float* __restrict__ bh, float* __restrict__ XP) {
  __shared__ float xs[8][256];

  const int tid = threadIdx.x;
  const size_t row0 = (size_t)blockIdx.x * 8;

  const float4* src = (const float4*)(X + row0 * 256);
  float4* dst = (float4*)&xs[0][0];
  dst[tid] = src[tid];
  dst[256 + tid] = src[256 + tid];
  __syncthreads();

  const int h = tid;
  float acc[8] = {0.f, 0.f, 0.f, 0.f, 0.f, 0.f, 0.f, 0.f};

#pragma unroll 4
  for (int i = 0; i < 256; ++i) {
    float u = Ux[i * 256 + h];
#pragma unroll
    for (int r = 0; r < 8; ++r)
      acc[r] = __fmaf_rn(xs[r][i], u, acc[r]);   // ascending i, single acc
  }

  const float b = bh[h];
#pragma unroll
  for (int r = 0; r < 8; ++r)
    XP[(row0 + r) * 256 + h] = __fadd_rn(acc[r], b);
}

// ---------------------------------------------------------------------------
// K2: scan, 2 rows/block. Thread j owns column j for BOTH rows; Wh[:,j] in
// AGPRs a0..a255 (shared). Two interleaved ascending-k chains (accA, accB),
// each bit-exact. h pipelines distance-8 per row. One barrier per step.
// ---------------------------------------------------------------------------
#define WLD(K) { float wt = Wh[(K) * 256 + j]; \
  asm volatile("v_accvgpr_write_b32 a" #K ", %0" :: "v"(wt) : "a" #K); }
#define WLD4(K0,K1,K2,K3) WLD(K0) WLD(K1) WLD(K2) WLD(K3)

#define WR1(K, D) asm volatile("v_accvgpr_read_b32 %0, a" #K : "=v"(D));

// Group: 4 k-values. Reads of NEXT group's weights interleaved; each current
// weight CW feeds chain A then chain B. Refill both h buffers at group end.
#define GRP2F(HA, HB, CW0,CW1,CW2,CW3, NK0,NK1,NK2,NK3, NW0,NW1,NW2,NW3, NQ) { \
  accA = __fmaf_rn(HA.x, CW0, accA); WR1(NK0, NW0) accB = __fmaf_rn(HB.x, CW0, accB); \
  accA = __fmaf_rn(HA.y, CW1, accA); WR1(NK1, NW1) accB = __fmaf_rn(HB.y, CW1, accB); \
  accA = __fmaf_rn(HA.z, CW2, accA); WR1(NK2, NW2) accB = __fmaf_rn(HB.z, CW2, accB); \
  accA = __fmaf_rn(HA.w, CW3, accA); WR1(NK3, NW3) accB = __fmaf_rn(HB.w, CW3, accB); \
  HA = hA4[NQ]; HB = hB4[NQ]; }

#define GRP2N(HA, HB, CW0,CW1,CW2,CW3, NK0,NK1,NK2,NK3, NW0,NW1,NW2,NW3) { \
  accA = __fmaf_rn(HA.x, CW0, accA); WR1(NK0, NW0) accB = __fmaf_rn(HB.x, CW0, accB); \
  accA = __fmaf_rn(HA.y, CW1, accA); WR1(NK1, NW1) accB = __fmaf_rn(HB.y, CW1, accB); \
  accA = __fmaf_rn(HA.z, CW2, accA); WR1(NK2, NW2) accB = __fmaf_rn(HB.z, CW2, accB); \
  accA = __fmaf_rn(HA.w, CW3, accA); WR1(NK3, NW3) accB = __fmaf_rn(HB.w, CW3, accB); }

#define GRP2E(HA, HB, CW0,CW1,CW2,CW3) { \
  accA = __fmaf_rn(HA.x, CW0, accA); accB = __fmaf_rn(HB.x, CW0, accB); \
  accA = __fmaf_rn(HA.y, CW1, accA); accB = __fmaf_rn(HB.y, CW1, accB); \
  accA = __fmaf_rn(HA.z, CW2, accA); accB = __fmaf_rn(HB.z, CW2, accB); \
  accA = __fmaf_rn(HA.w, CW3, accA); accB = __fmaf_rn(HB.w, CW3, accB); }

__global__ __launch_bounds__(256)
__attribute__((amdgpu_waves_per_eu(1, 1)))
void scan_xla_kernel(
    const float* __restrict__ Wh, const float* __restrict__ h0,
    float* __restrict__ xpH, float* __restrict__ hfinal) {
  __shared__ float hA0[256], hA1[256];
  __shared__ float hB0[256], hB1[256];

  const int j = threadIdx.x;
  const int rA = blockIdx.x * 2;
  const int rB = rA + 1;

  // ---- load Wh[:,j] into a0..a255 (shared by both rows) ----
  WLD4(0,1,2,3)       WLD4(4,5,6,7)       WLD4(8,9,10,11)     WLD4(12,13,14,15)
  WLD4(16,17,18,19)   WLD4(20,21,22,23)   WLD4(24,25,26,27)   WLD4(28,29,30,31)
  WLD4(32,33,34,35)   WLD4(36,37,38,39)   WLD4(40,41,42,43)   WLD4(44,45,46,47)
  WLD4(48,49,50,51)   WLD4(52,53,54,55)   WLD4(56,57,58,59)   WLD4(60,61,62,63)
  WLD4(64,65,66,67)   WLD4(68,69,70,71)   WLD4(72,73,74,75)   WLD4(76,77,78,79)
  WLD4(80,81,82,83)   WLD4(84,85,86,87)   WLD4(88,89,90,91)   WLD4(92,93,94,95)
  WLD4(96,97,98,99)   WLD4(100,101,102,103) WLD4(104,105,106,107) WLD4(108,109,110,111)
  WLD4(112,113,114,115) WLD4(116,117,118,119) WLD4(120,121,122,123) WLD4(124,125,126,127)
  WLD4(128,129,130,131) WLD4(132,133,134,135) WLD4(136,137,138,139) WLD4(140,141,142,143)
  WLD4(144,145,146,147) WLD4(148,149,150,151) WLD4(152,153,154,155) WLD4(156,157,158,159)
  WLD4(160,161,162,163) WLD4(164,165,166,167) WLD4(168,169,170,171) WLD4(172,173,174,175)
  WLD4(176,177,178,179) WLD4(180,181,182,183) WLD4(184,185,186,187) WLD4(188,189,190,191)
  WLD4(192,193,194,195) WLD4(196,197,198,199) WLD4(200,201,202,203) WLD4(204,205,206,207)
  WLD4(208,209,210,211) WLD4(212,213,214,215) WLD4(216,217,218,219) WLD4(220,221,222,223)
  WLD4(224,225,226,227) WLD4(228,229,230,231) WLD4(232,233,234,235) WLD4(236,237,238,239)
  WLD4(240,241,242,243) WLD4(244,245,246,247) WLD4(248,249,250,251) WLD4(252,253,254,255)

  hA0[j] = h0[rA * 256 + j];
  hB0[j] = h0[rB * 256 + j];
  __syncthreads();

  float xpA = xpH[(size_t)rA * 256 + j];
  float xpB = xpH[(size_t)rB * 256 + j];
  float hnA_prev = 0.f, hnB_prev = 0.f;
  const float* curA = hA0; float* nxtA = hA1;
  const float* curB = hB0; float* nxtB = hB1;

  for (int t = 0; t < SEQ; ++t) {
    if (t > 0) {
      xpH[(size_t)(t - 1) * BH + rA * 256 + j] = hnA_prev;
      xpH[(size_t)(t - 1) * BH + rB * 256 + j] = hnB_prev;
    }
    float xpA_n = (t + 1 < SEQ) ? xpH[(size_t)(t + 1) * BH + rA * 256 + j] : 0.f;
    float xpB_n = (t + 1 < SEQ) ? xpH[(size_t)(t + 1) * BH + rB * 256 + j] : 0.f;

    const float4* hA4 = (const float4*)curA;
    const float4* hB4 = (const float4*)curB;
    float4 a0_ = hA4[0], a1_ = hA4[1], a2_ = hA4[2], a3_ = hA4[3];
    float4 a4_ = hA4[4], a5_ = hA4[5], a6_ = hA4[6], a7_ = hA4[7];
    float4 b0_ = hB4[0], b1_ = hB4[1], b2_ = hB4[2], b3_ = hB4[3];
    float4 b4_ = hB4[4], b5_ = hB4[5], b6_ = hB4[6], b7_ = hB4[7];

    float wa0, wa1, wa2, wa3, wb0, wb1, wb2, wb3;
    WR1(0, wa0) WR1(1, wa1) WR1(2, wa2) WR1(3, wa3)

    float accA = 0.f, accB = 0.f;
    GRP2F(a0_, b0_, wa0,wa1,wa2,wa3,   4,5,6,7,     wb0,wb1,wb2,wb3,  8)
    GRP2F(a1_, b1_, wb0,wb1,wb2,wb3,   8,9,10,11,   wa0,wa1,wa2,wa3,  9)
    GRP2F(a2_, b2_, wa0,wa1,wa2,wa3,   12,13,14,15, wb0,wb1,wb2,wb3, 10)
    GRP2F(a3_, b3_, wb0,wb1,wb2,wb3,   16,17,18,19, wa0,wa1,wa2,wa3, 11)
    GRP2F(a4_, b4_, wa0,wa1,wa2,wa3,   20,21,22,23, wb0,wb1,wb2,wb3, 12)
    GRP2F(a5_, b5_, wb0,wb1,wb2,wb3,   24,25,26,27, wa0,wa1,wa2,wa3, 13)
    GRP2F(a6_, b6_, wa0,wa1,wa2,wa3,   28,29,30,31, wb0,wb1,wb2,wb3, 14)
    GRP2F(a7_, b7_, wb0,wb1,wb2,wb3,   32,33,34,35, wa0,wa1,wa2,wa3, 15)
    GRP2F(a0_, b0_, wa0,wa1,wa2,wa3,   36,37,38,39, wb0,wb1,wb2,wb3, 16)
    GRP2F(a1_, b1_, wb0,wb1,wb2,wb3,   40,41,42,43, wa0,wa1,wa2,wa3, 17)
    GRP2F(a2_, b2_, wa0,wa1,wa2,wa3,   44,45,46,47, wb0,wb1,wb2,wb3, 18)
    GRP2F(a3_, b3_, wb0,wb1,wb2,wb3,   48,49,50,51, wa0,wa1,wa2,wa3, 19)
    GRP2F(a4_, b4_, wa0,wa1,wa2,wa3,   52,53,54,55, wb0,wb1,wb2,wb3, 20)
    GRP2F(a5_, b5_, wb0,wb1,wb2,wb3,   56,57,58,59, wa0,wa1,wa2,wa3, 21)
    GRP2F(a6_, b6_, wa0,wa1,wa2,wa3,   60,61,62,63, wb0,wb1,wb2,wb3, 22)
    GRP2F(a7_, b7_, wb0,wb1,wb2,wb3,   64,65,66,67, wa0,wa1,wa2,wa3, 23)
    GRP2F(a0_, b0_, wa0,wa1,wa2,wa3,   68,69,70,71, wb0,wb1,wb2,wb3, 24)
    GRP2F(a1_, b1_, wb0,wb1,wb2,wb3,   72,73,74,75, wa0,wa1,wa2,wa3, 25)
    GRP2F(a2_, b2_, wa0,wa1,wa2,wa3,   76,77,78,79, wb0,wb1,wb2,wb3, 26)
    GRP2F(a3_, b3_, wb0,wb1,wb2,wb3,   80,81,82,83, wa0,wa1,wa2,wa3, 27)
    GRP2F(a4_, b4_, wa0,wa1,wa2,wa3,   84,85,86,87, wb0,wb1,wb2,wb3, 28)
    GRP2F(a5_, b5_, wb0,wb1,wb2,wb3,   88,89,90,91, wa0,wa1,wa2,wa3, 29)
    GRP2F(a6_, b6_, wa0,wa1,wa2,wa3,   92,93,94,95, wb0,wb1,wb2,wb3, 30)
    GRP2F(a7_, b7_, wb0,wb1,wb2,wb3,   96,97,98,99, wa0,wa1,wa2,wa3, 31)
    GRP2F(a0_, b0_, wa0,wa1,wa2,wa3,   100,101,102,103, wb0,wb1,wb2,wb3, 32)
    GRP2F(a1_, b1_, wb0,wb1,wb2,wb3,   104,105,106,107, wa0,wa1,wa2,wa3, 33)
    GRP2F(a2_, b2_, wa0,wa1,wa2,wa3,   108,109,110,111, wb0,wb1,wb2,wb3, 34)
    GRP2F(a3_, b3_, wb0,wb1,wb2,wb3,   112,113,114,115, wa0,wa1,wa2,wa3, 35)
    GRP2F(a4_, b4_, wa0,wa1,wa2,wa3,   116,117,118,119, wb0,wb1,wb2,wb3, 36)
    GRP2F(a5_, b5_, wb0,wb1,wb2,wb3,   120,121,122,123, wa0,wa1,wa2,wa3, 37)
    GRP2F(a6_, b6_, wa0,wa1,wa2,wa3,   124,125,126,127, wb0,wb1,wb2,wb3, 38)
    GRP2F(a7_, b7_, wb0,wb1,wb2,wb3,   128,129,130,131, wa0,wa1,wa2,wa3, 39)
    GRP2F(a0_, b0_, wa0,wa1,wa2,wa3,   132,133,134,135, wb0,wb1,wb2,wb3, 40)
    GRP2F(a1_, b1_, wb0,wb1,wb2,wb3,   136,137,138,139, wa0,wa1,wa2,wa3, 41)
    GRP2F(a2_, b2_, wa0,wa1,wa2,wa3,   140,141,142,143, wb0,wb1,wb2,wb3, 42)
    GRP2F(a3_, b3_, wb0,wb1,wb2,wb3,   144,145,146,147, wa0,wa1,wa2,wa3, 43)
    GRP2F(a4_, b4_, wa0,wa1,wa2,wa3,   148,149,150,151, wb0,wb1,wb2,wb3, 44)
    GRP2F(a5_, b5_, wb0,wb1,wb2,wb3,   152,153,154,155, wa0,wa1,wa2,wa3, 45)
    GRP2F(a6_, b6_, wa0,wa1,wa2,wa3,   156,157,158,159, wb0,wb1,wb2,wb3, 46)
    GRP2F(a7_, b7_, wb0,wb1,wb2,wb3,   160,161,162,163, wa0,wa1,wa2,wa3, 47)
    GRP2F(a0_, b0_, wa0,wa1,wa2,wa3,   164,165,166,167, wb0,wb1,wb2,wb3, 48)
    GRP2F(a1_, b1_, wb0,wb1,wb2,wb3,   168,169,170,171, wa0,wa1,wa2,wa3, 49)
    GRP2F(a2_, b2_, wa0,wa1,wa2,wa3,   172,173,174,175, wb0,wb1,wb2,wb3, 50)
    GRP2F(a3_, b3_, wb0,wb1,wb2,wb3,   176,177,178,179, wa0,wa1,wa2,wa3, 51)
    GRP2F(a4_, b4_, wa0,wa1,wa2,wa3,   180,181,182,183, wb0,wb1,wb2,wb3, 52)
    GRP2F(a5_, b5_, wb0,wb1,wb2,wb3,   184,185,186,187, wa0,wa1,wa2,wa3, 53)
    GRP2F(a6_, b6_, wa0,wa1,wa2,wa3,   188,189,190,191, wb0,wb1,wb2,wb3, 54)
    GRP2F(a7_, b7_, wb0,wb1,wb2,wb3,   192,193,194,195, wa0,wa1,wa2,wa3, 55)
    GRP2F(a0_, b0_, wa0,wa1,wa2,wa3,   196,197,198,199, wb0,wb1,wb2,wb3, 56)
    GRP2F(a1_, b1_, wb0,wb1,wb2,wb3,   200,201,202,203, wa0,wa1,wa2,wa3, 57)
    GRP2F(a2_, b2_, wa0,wa1,wa2,wa3,   204,205,206,207, wb0,wb1,wb2,wb3, 58)
    GRP2F(a3_, b3_, wb0,wb1,wb2,wb3,   208,209,210,211, wa0,wa1,wa2,wa3, 59)
    GRP2F(a4_, b4_, wa0,wa1,wa2,wa3,   212,213,214,215, wb0,wb1,wb2,wb3, 60)
    GRP2F(a5_, b5_, wb0,wb1,wb2,wb3,   216,217,218,219, wa0,wa1,wa2,wa3, 61)
    GRP2F(a6_, b6_, wa0,wa1,wa2,wa3,   220,221,222,223, wb0,wb1,wb2,wb3, 62)
    GRP2F(a7_, b7_, wb0,wb1,wb2,wb3,   224,225,226,227, wa0,wa1,wa2,wa3, 63)
    GRP2N(a0_, b0_, wa0,wa1,wa2,wa3,   228,229,230,231, wb0,wb1,wb2,wb3)
    GRP2N(a1_, b1_, wb0,wb1,wb2,wb3,   232,233,234,235, wa0,wa1,wa2,wa3)
    GRP2N(a2_, b2_, wa0,wa1,wa2,wa3,   236,237,238,239, wb0,wb1,wb2,wb3)
    GRP2N(a3_, b3_, wb0,wb1,wb2,wb3,   240,241,242,243, wa0,wa1,wa2,wa3)
    GRP2N(a4_, b4_, wa0,wa1,wa2,wa3,   244,245,246,247, wb0,wb1,wb2,wb3)
    GRP2N(a5_, b5_, wb0,wb1,wb2,wb3,   248,249,250,251, wa0,wa1,wa2,wa3)
    GRP2N(a6_, b6_, wa0,wa1,wa2,wa3,   252,253,254,255, wb0,wb1,wb2,wb3)
    GRP2E(a7_, b7_, wb0,wb1,wb2,wb3)

    float zA = __fadd_rn(xpA, accA);
    float zB = __fadd_rn(xpB, accB);
    float hnA = tanh_xla(zA);
    float hnB = tanh_xla(zB);

    nxtA[j] = hnA;
    nxtB[j] = hnB;
    __syncthreads();

    { const float* t_ = curA; curA = nxtA; nxtA = (float*)t_; }
    { const float* t_ = curB; curB = nxtB; nxtB = (float*)t_; }
    xpA = xpA_n; xpB = xpB_n;
    hnA_prev = hnA; hnB_prev = hnB;
  }

  xpH[(size_t)(SEQ - 1) * BH + rA * 256 + j] = hnA_prev;
  xpH[(size_t)(SEQ - 1) * BH + rB * 256 + j] = hnB_prev;
  hfinal[rA * 256 + j] = hnA_prev;
  hfinal[rB * 256 + j] = hnB_prev;
}

// ---------------------------------------------------------------------------
// K3: in-place fp32 GEMM: rows of HO (M x 256) -> row @ Vo + co.
// Outside the feedback loop => rounding free. Block stages its own 64 rows
// in LDS then overwrites exactly those rows (race-free).
// ---------------------------------------------------------------------------
__global__ __launch_bounds__(256) void gemm_inplace_kernel(
    float* __restrict__ HO, const float* __restrict__ Vo,
    const float* __restrict__ co) {
  __shared__ float Hs[64][260];
  __shared__ float Bs[32][64];

  const int tid = threadIdx.x;
  const int bm = blockIdx.x;
  float* base = HO + (size_t)bm * 64 * 256;

#pragma unroll
  for (int l = 0; l < 16; ++l) {
    int idx = l * 256 + tid;
    int r = idx >> 6;
    int c4 = idx & 63;
    float4 v = *(const float4*)&base[r * 256 + c4 * 4];
    *(float4*)&Hs[r][c4 * 4] = v;
  }

  const int tr = tid >> 4;
  const int tc = tid & 15;

  for (int bn = 0; bn < 4; ++bn) {
    float acc[4][4];
#pragma unroll
    for (int i = 0; i < 4; ++i)
#pragma unroll
      for (int j = 0; j < 4; ++j) acc[i][j] = 0.f;

    for (int kt = 0; kt < 256; kt += 32) {
      __syncthreads();
#pragma unroll
      for (int l = 0; l < 2; ++l) {
        int idx = tid * 2 + l;
        int k2 = idx >> 4;
        int nn = (idx & 15) << 2;
        float4 bv = *(const float4*)&Vo[(size_t)(kt + k2) * 256 + bn * 64 + nn];
        *(float4*)&Bs[k2][nn] = bv;
      }
      __syncthreads();
#pragma unroll
      for (int k = 0; k < 32; ++k) {
        float4 bq = *(const float4*)&Bs[k][tc * 4];
        float bv[4] = {bq.x, bq.y, bq.z, bq.w};
#pragma unroll
        for (int i = 0; i < 4; ++i) {
          float a = Hs[tr * 4 + i][kt + k];
#pragma unroll
          for (int j = 0; j < 4; ++j) acc[i][j] += a * bv[j];
        }
      }
    }

    const float4 cb = *(const float4*)&co[bn * 64 + tc * 4];
    const float cv[4] = {cb.x, cb.y, cb.z, cb.w};
#pragma unroll
    for (int i = 0; i < 4; ++i) {
      float4 o;
      o.x = acc[i][0] + cv[0];
      o.y = acc[i][1] + cv[1];
      o.z = acc[i][2] + cv[2];
      o.w = acc[i][3] + cv[3];
      *(float4*)&base[(tr * 4 + i) * 256 + bn * 64 + tc * 4] = o;
    }
  }
}

extern "C" void kernel_launch(void* const* d_in, const int* in_sizes, int n_in,
                              void* d_out, int out_size, void* d_ws, size_t ws_size,
                              hipStream_t stream) {
  const float* inputs = (const float*)d_in[0];
  const float* h0     = (const float*)d_in[1];
  const float* Wh     = (const float*)d_in[2];
  const float* Ux     = (const float*)d_in[3];
  const float* bh     = (const float*)d_in[4];
  const float* Vo     = (const float*)d_in[5];
  const float* co     = (const float*)d_in[6];

  float* out = (float*)d_out;                       // outputs (S,B,O)
  float* hfinal = out + (size_t)SEQ * BATCH * 256;  // ht_final (B,H)
  (void)d_ws; (void)ws_size;

  const int M = SEQ * BATCH;  // 131072 rows

  // K1: xp (Eigen-order FMA chain + bias add) -> d_out outputs region
  xp_dot_kernel<<<M / 8, 256, 0, stream>>>(inputs, Ux, bh, out);

  // K2: XLA-exact scan, 2 rows/block, shared AGPR weights, dual chains.
  scan_xla_kernel<<<BATCH / 2, 256, 0, stream>>>(Wh, h0, out, hfinal);

  // K3: in-place outputs = H @ Vo + co.
  gemm_inplace_kernel<<<M / 64, 256, 0, stream>>>(out, Vo, co);
}